// Round 6
// baseline (135.723 us; speedup 1.0000x reference)
//
#include <hip/hip_runtime.h>
#include <math.h>

namespace {
constexpr int B = 32, C = 2, T = 262144, K = 6;
constexpr int NBC = B * C;          // 64 rows (b,c)
constexpr int NST = 2 * K;          // 12-dim cascade state
constexpr int PB = 8;               // blocks per row (chain length)
constexpr int CH = T / PB;          // 32768 samples per block
constexpr int NW = 4;               // waves per block (256 threads)
constexpr int SEGL = CH / (NW * 64);// 128 samples per thread-segment
constexpr int TS = 16;              // samples per staging tile
constexpr int NT = SEGL / TS;       // 8 tiles
constexpr int Q4 = SEGL / 4;        // 32 float4 per segment
constexpr int SQ1 = 7;              // A -> A^128
constexpr int SQ2 = 6;              // -> A^8192 (wave span)
constexpr int SQ3 = 2;              // -> A^32768 (block span)
constexpr float FS = 44100.0f;
// ws float offsets
constexpr size_t OFF_CF = 0;                  // 32*30 = 960
constexpr size_t OFF_RL = 960;                // 32*144
constexpr size_t OFF_RW = OFF_RL + 4608;
constexpr size_t OFF_RC = OFF_RW + 4608;
constexpr size_t OFF_ST = OFF_RC + 4608;      // 512*12 states
constexpr size_t OFF_FL = OFF_ST + 6144;      // 512 uint flags
}

__device__ __forceinline__ float rl(float v, int lane) {
  return __int_as_float(__builtin_amdgcn_readlane(__float_as_int(v), lane));
}

// one affine-scan step: component-l lane holds s; returns (M*s)[l], M in row form
__device__ __forceinline__ float mv_step(const float (&row)[NST], float sv) {
  float t0 = fmaf(row[0], rl(sv, 0), fmaf(row[1], rl(sv, 1), row[2] * rl(sv, 2)));
  float t1 = fmaf(row[3], rl(sv, 3), fmaf(row[4], rl(sv, 4), row[5] * rl(sv, 5)));
  float t2 = fmaf(row[6], rl(sv, 6), fmaf(row[7], rl(sv, 7), row[8] * rl(sv, 8)));
  float t3 = fmaf(row[9], rl(sv, 9), fmaf(row[10], rl(sv, 10), row[11] * rl(sv, 11)));
  return (t0 + t1) + (t2 + t3);
}

// Prep: per b, RBJ coeffs + A^128 / A^8192 / A^32768 in row-major form.
__global__ __launch_bounds__(64) void eq_prep(const float* __restrict__ fr,
                                              const float* __restrict__ gn,
                                              const float* __restrict__ qf,
                                              float* __restrict__ ws) {
  int b = blockIdx.x;
  int l = threadIdx.x;
  float* cf = ws + OFF_CF;

  float cb0[K], cb1[K], cb2[K], ca1[K], ca2[K];
#pragma unroll
  for (int k = 0; k < K; ++k) {
    float f = fr[b * K + k], g = gn[b * K + k], Q = qf[b * K + k];
    float A  = powf(10.0f, g * (1.0f / 40.0f));
    float w0 = 6.283185307179586f * f / FS;
    float cw = cosf(w0);
    float al = sinf(w0) / (2.0f * Q);
    float ia = 1.0f / (1.0f + al / A);
    cb0[k] = (1.0f + al * A) * ia;
    cb1[k] = (-2.0f * cw) * ia;
    cb2[k] = (1.0f - al * A) * ia;
    ca1[k] = (-2.0f * cw) * ia;
    ca2[k] = (1.0f - al / A) * ia;
  }
#pragma unroll
  for (int k = 0; k < K; ++k) {
    if (l == k) {
      float* p = cf + (b * K + k) * 5;
      p[0] = cb0[k]; p[1] = cb1[k]; p[2] = cb2[k]; p[3] = ca1[k]; p[4] = ca2[k];
    }
  }

  // column l of one-sample homogeneous map A
  float col[NST];
  {
    float s1[K], s2[K];
#pragma unroll
    for (int k = 0; k < K; ++k) {
      s1[k] = (l == 2 * k) ? 1.0f : 0.0f;
      s2[k] = (l == 2 * k + 1) ? 1.0f : 0.0f;
    }
    float yv = 0.0f;
#pragma unroll
    for (int k = 0; k < K; ++k) {
      float yk = fmaf(cb0[k], yv, s1[k]);
      float t1 = fmaf(cb1[k], yv, s2[k]);
      float ns1 = fmaf(-ca1[k], yk, t1);
      float ns2 = fmaf(-ca2[k], yk, cb2[k] * yv);
      s1[k] = ns1; s2[k] = ns2; yv = yk;
    }
#pragma unroll
    for (int k = 0; k < K; ++k) { col[2 * k] = s1[k]; col[2 * k + 1] = s2[k]; }
  }

  auto square = [&]() {
    float nc[NST];
#pragma unroll
    for (int r = 0; r < NST; ++r) nc[r] = 0.0f;
#pragma unroll
    for (int m = 0; m < NST; ++m) {
      float wv = col[m];
#pragma unroll
      for (int r = 0; r < NST; ++r) nc[r] = fmaf(rl(col[r], m), wv, nc[r]);
    }
#pragma unroll
    for (int r = 0; r < NST; ++r) col[r] = nc[r];
  };
  auto dump = [&](float* G) {
    if (l < NST) {
#pragma unroll
      for (int r = 0; r < NST; ++r) G[(size_t)b * 144 + r * 12 + l] = col[r];
    }
  };

  for (int p = 0; p < SQ1; ++p) square();
  dump(ws + OFF_RL);
  for (int p = 0; p < SQ2; ++p) square();
  dump(ws + OFF_RW);
  for (int p = 0; p < SQ3; ++p) square();
  dump(ws + OFF_RC);
}

// Fused: phase1 zero-state finals -> block scan -> inter-block chain handshake
// -> exact incoming per thread -> phase3 output from L3-warm re-read of x.
__global__ __launch_bounds__(256, 2) void eq_fused(const float* __restrict__ x,
                                                   float* __restrict__ ws,
                                                   float* __restrict__ y) {
  __shared__ float P1[NW][2][64][17];       // input staging (34816 B)
  __shared__ float U[NW * 2 * 64 * 17];     // scan structs / output staging
  __shared__ float BIN[16];                 // block incoming state

  const float* cf = ws + OFF_CF;
  float* states = ws + OFF_ST;
  unsigned* flags = (unsigned*)(ws + OFF_FL);

  int t = threadIdx.x, w = t >> 6, l = t & 63;
  int blk = blockIdx.x, row = blk / PB, p = blk % PB, b = row >> 1;
  bool act = (l < NST);

  // U overlays: phase2 = FB | SL | WF ; phase3 = sOut
  auto FBp = [&](int ww, int i, int r) -> float& { return U[(ww * 64 + i) * 13 + r]; };
  auto SLp = [&](int ww, int i, int r) -> float& { return U[3328 + (ww * 64 + i) * 13 + r]; };
  auto WFp = [&](int ww, int r) -> float& { return U[6656 + ww * 13 + r]; };
  auto SO = [&](int pb, int seg, int c) -> float& { return U[((w * 2 + pb) * 64 + seg) * 17 + c]; };

  const float4* xq = reinterpret_cast<const float4*>(
      x + (size_t)row * T + (size_t)p * CH + (size_t)w * (64 * SEGL));
  float4* yq = reinterpret_cast<float4*>(
      y + (size_t)row * T + (size_t)p * CH + (size_t)w * (64 * SEGL));

  int sj = l >> 2, qj = l & 3;

  // phase-1 prologue loads first (hide coeff/matrix loads under them)
  float4 ra[4], rb[4];
#pragma unroll
  for (int j = 0; j < 4; ++j) ra[j] = xq[(size_t)(j * 16 + sj) * Q4 + qj];
#pragma unroll
  for (int j = 0; j < 4; ++j) rb[j] = xq[(size_t)(j * 16 + sj) * Q4 + 4 + qj];

  float b0[K], b1c[K], b2c[K], a1c[K], a2c[K];
#pragma unroll
  for (int k = 0; k < K; ++k) {
    const float* cp = cf + (b * K + k) * 5;
    b0[k] = cp[0]; b1c[k] = cp[1]; b2c[k] = cp[2]; a1c[k] = cp[3]; a2c[k] = cp[4];
  }
  float rowL[NST], rowW[NST], rowC[NST];
#pragma unroll
  for (int m = 0; m < NST; ++m) {
    rowL[m] = act ? ws[OFF_RL + (size_t)b * 144 + l * 12 + m] : 0.0f;
    rowW[m] = act ? ws[OFF_RW + (size_t)b * 144 + l * 12 + m] : 0.0f;
    rowC[m] = act ? ws[OFF_RC + (size_t)b * 144 + l * 12 + m] : 0.0f;
  }

  float s1[K], s2[K];
#pragma unroll
  for (int k = 0; k < K; ++k) { s1[k] = 0.0f; s2[k] = 0.0f; }

  auto stage = [&](float4 (&r)[4], int pb) {
#pragma unroll
    for (int j = 0; j < 4; ++j) {
      int seg = j * 16 + sj;
      P1[w][pb][seg][qj * 4 + 0] = r[j].x;
      P1[w][pb][seg][qj * 4 + 1] = r[j].y;
      P1[w][pb][seg][qj * 4 + 2] = r[j].z;
      P1[w][pb][seg][qj * 4 + 3] = r[j].w;
    }
  };
  auto prefetch = [&](float4 (&r)[4], int tnext) {
    if (tnext < NT) {
#pragma unroll
      for (int j = 0; j < 4; ++j)
        r[j] = xq[(size_t)(j * 16 + sj) * Q4 + (size_t)tnext * 4 + qj];
    }
  };

  // ---- phase 1: zero-state pass, record per-thread finals
  for (int tt = 0; tt < NT; tt += 2) {
    stage(ra, 0);
    prefetch(ra, tt + 2);
#pragma unroll
    for (int i = 0; i < TS; ++i) {
      float yv = P1[w][0][l][i];
#pragma unroll
      for (int k = 0; k < K; ++k) {
        float yk = fmaf(b0[k], yv, s1[k]);
        float t1 = fmaf(b1c[k], yv, s2[k]);
        s1[k] = fmaf(-a1c[k], yk, t1);
        s2[k] = fmaf(-a2c[k], yk, b2c[k] * yv);
        yv = yk;
      }
    }
    stage(rb, 1);
    prefetch(rb, tt + 3);
#pragma unroll
    for (int i = 0; i < TS; ++i) {
      float yv = P1[w][1][l][i];
#pragma unroll
      for (int k = 0; k < K; ++k) {
        float yk = fmaf(b0[k], yv, s1[k]);
        float t1 = fmaf(b1c[k], yv, s2[k]);
        s1[k] = fmaf(-a1c[k], yk, t1);
        s2[k] = fmaf(-a2c[k], yk, b2c[k] * yv);
        yv = yk;
      }
    }
  }
#pragma unroll
  for (int k = 0; k < K; ++k) { FBp(w, l, 2 * k) = s1[k]; FBp(w, l, 2 * k + 1) = s2[k]; }
  __syncthreads();

  // ---- C1a: wave scan (zero incoming) -> wave final
  {
    float sv = 0.0f;
    for (int i = 0; i < 64; ++i) {
      float wv = act ? FBp(w, i, l) : 0.0f;
      sv = mv_step(rowL, sv) + wv;
    }
    if (act) WFp(w, l) = sv;
  }
  __syncthreads();

  // issue phase-3 prologue loads now (hide under handshake latency)
#pragma unroll
  for (int j = 0; j < 4; ++j) ra[j] = xq[(size_t)(j * 16 + sj) * Q4 + qj];
#pragma unroll
  for (int j = 0; j < 4; ++j) rb[j] = xq[(size_t)(j * 16 + sj) * Q4 + 4 + qj];

  // ---- handshake (wave 0): chain incoming through the row's 8 blocks
  if (w == 0) {
    float bz = 0.0f;
#pragma unroll
    for (int w2 = 0; w2 < NW; ++w2) {
      float wv = act ? WFp(w2, l) : 0.0f;
      bz = mv_step(rowW, bz) + wv;
    }
    float bin = 0.0f;
    if (p > 0) {
      if (l == 0) {
        while (atomicAdd(&flags[blk - 1], 0u) == 0u) { __builtin_amdgcn_s_sleep(8); }
      }
      __threadfence();
      if (act) bin = atomicAdd(&states[(size_t)(blk - 1) * NST + l], 0.0f);
    }
    if (p < PB - 1) {
      float bout = mv_step(rowC, bin) + bz;
      if (act) atomicExch(&states[(size_t)blk * NST + l], bout);
      __threadfence();
      if (l == 0) atomicExch(&flags[blk], 1u);
    }
    if (act) BIN[l] = bin;
  }
  __syncthreads();

  // ---- per-wave true incoming, then C1b stores per-segment incoming
  {
    float sv = act ? BIN[l] : 0.0f;
    for (int w2 = 0; w2 < w; ++w2) {
      float wv = act ? WFp(w2, l) : 0.0f;
      sv = mv_step(rowW, sv) + wv;
    }
    for (int i = 0; i < 64; ++i) {
      if (act) SLp(w, i, l) = sv;
      float wv = act ? FBp(w, i, l) : 0.0f;
      sv = mv_step(rowL, sv) + wv;
    }
  }
  // extract own incoming before U is reused as sOut
  float st[NST];
#pragma unroll
  for (int r = 0; r < NST; ++r) st[r] = SLp(w, l, r);
  __syncthreads();

  // ---- phase 3: exact pass, write output through full-line staging
#pragma unroll
  for (int k = 0; k < K; ++k) { s1[k] = st[2 * k]; s2[k] = st[2 * k + 1]; }

  auto flush = [&](int pb, int tt) {
#pragma unroll
    for (int j = 0; j < 4; ++j) {
      int seg = j * 16 + sj;
      float4 o;
      o.x = SO(pb, seg, qj * 4 + 0);
      o.y = SO(pb, seg, qj * 4 + 1);
      o.z = SO(pb, seg, qj * 4 + 2);
      o.w = SO(pb, seg, qj * 4 + 3);
      yq[(size_t)seg * Q4 + (size_t)tt * 4 + qj] = o;
    }
  };

  for (int tt = 0; tt < NT; tt += 2) {
    stage(ra, 0);
    prefetch(ra, tt + 2);
#pragma unroll
    for (int i = 0; i < TS; ++i) {
      float yv = P1[w][0][l][i];
#pragma unroll
      for (int k = 0; k < K; ++k) {
        float yk = fmaf(b0[k], yv, s1[k]);
        float t1 = fmaf(b1c[k], yv, s2[k]);
        s1[k] = fmaf(-a1c[k], yk, t1);
        s2[k] = fmaf(-a2c[k], yk, b2c[k] * yv);
        yv = yk;
      }
      SO(0, l, i) = yv;
    }
    flush(0, tt);
    stage(rb, 1);
    prefetch(rb, tt + 3);
#pragma unroll
    for (int i = 0; i < TS; ++i) {
      float yv = P1[w][1][l][i];
#pragma unroll
      for (int k = 0; k < K; ++k) {
        float yk = fmaf(b0[k], yv, s1[k]);
        float t1 = fmaf(b1c[k], yv, s2[k]);
        s1[k] = fmaf(-a1c[k], yk, t1);
        s2[k] = fmaf(-a2c[k], yk, b2c[k] * yv);
        yv = yk;
      }
      SO(1, l, i) = yv;
    }
    flush(1, tt + 1);
  }
}

extern "C" void kernel_launch(void* const* d_in, const int* in_sizes, int n_in,
                              void* d_out, int out_size, void* d_ws, size_t ws_size,
                              hipStream_t stream) {
  const float* audio = (const float*)d_in[0];
  const float* fr    = (const float*)d_in[1];
  const float* gn    = (const float*)d_in[2];
  const float* qf    = (const float*)d_in[3];
  float* out = (float*)d_out;
  float* ws = (float*)d_ws;

  // clear handshake flags (graph-capture-legal async memset)
  hipMemsetAsync((char*)d_ws + OFF_FL * sizeof(float), 0,
                 NBC * PB * sizeof(unsigned), stream);
  hipLaunchKernelGGL(eq_prep, dim3(B), dim3(64), 0, stream, fr, gn, qf, ws);
  hipLaunchKernelGGL(eq_fused, dim3(NBC * PB), dim3(256), 0, stream,
                     audio, ws, out);
}

// Round 7
// 107.438 us; speedup vs baseline: 1.2633x; 1.2633x over previous
//
#include <hip/hip_runtime.h>
#include <math.h>

namespace {
constexpr int B = 32, C = 2, T = 262144, K = 6;
constexpr int NBC = B * C;          // 64 rows (b,c)
constexpr int NST = 2 * K;          // 12-dim cascade state
constexpr int PB = 8;               // blocks per row
constexpr int CH = T / PB;          // 32768 samples per block
constexpr int NW = 4;               // waves per block (256 threads)
constexpr int SEGL = CH / (NW * 64);// 128 samples per thread-segment
constexpr int TS = 16;              // samples per staging tile
constexpr int NT = SEGL / TS;       // 8 tiles
constexpr int Q4 = SEGL / 4;        // 32 float4 per segment
constexpr int SQ1 = 7;              // A -> A^128
constexpr int SQ2 = 6;              // -> A^8192 (wave span)
constexpr int SQ3 = 2;              // -> A^32768 (block span)
constexpr float FS = 44100.0f;
// ws float offsets
constexpr size_t OFF_CF = 0;                  // 32*30 = 960
constexpr size_t OFF_RL = 960;                // 32*144
constexpr size_t OFF_RW = OFF_RL + 4608;
constexpr size_t OFF_RC = OFF_RW + 4608;
constexpr size_t OFF_ST = OFF_RC + 4608;      // 512*12 states
constexpr size_t OFF_FL = OFF_ST + 6144;      // 512 uint flags
}

__device__ __forceinline__ float rl(float v, int lane) {
  return __int_as_float(__builtin_amdgcn_readlane(__float_as_int(v), lane));
}

// one affine-scan step: component-l lane holds s; returns (M*s)[l], M in row form
__device__ __forceinline__ float mv_step(const float (&row)[NST], float sv) {
  float t0 = fmaf(row[0], rl(sv, 0), fmaf(row[1], rl(sv, 1), row[2] * rl(sv, 2)));
  float t1 = fmaf(row[3], rl(sv, 3), fmaf(row[4], rl(sv, 4), row[5] * rl(sv, 5)));
  float t2 = fmaf(row[6], rl(sv, 6), fmaf(row[7], rl(sv, 7), row[8] * rl(sv, 8)));
  float t3 = fmaf(row[9], rl(sv, 9), fmaf(row[10], rl(sv, 10), row[11] * rl(sv, 11)));
  return (t0 + t1) + (t2 + t3);
}

// Prep: per b, RBJ coeffs + A^128 / A^8192 / A^32768 in row-major form.
__global__ __launch_bounds__(64) void eq_prep(const float* __restrict__ fr,
                                              const float* __restrict__ gn,
                                              const float* __restrict__ qf,
                                              float* __restrict__ ws) {
  int b = blockIdx.x;
  int l = threadIdx.x;
  float* cf = ws + OFF_CF;

  float cb0[K], cb1[K], cb2[K], ca1[K], ca2[K];
#pragma unroll
  for (int k = 0; k < K; ++k) {
    float f = fr[b * K + k], g = gn[b * K + k], Q = qf[b * K + k];
    float A  = powf(10.0f, g * (1.0f / 40.0f));
    float w0 = 6.283185307179586f * f / FS;
    float cw = cosf(w0);
    float al = sinf(w0) / (2.0f * Q);
    float ia = 1.0f / (1.0f + al / A);
    cb0[k] = (1.0f + al * A) * ia;
    cb1[k] = (-2.0f * cw) * ia;
    cb2[k] = (1.0f - al * A) * ia;
    ca1[k] = (-2.0f * cw) * ia;
    ca2[k] = (1.0f - al / A) * ia;
  }
#pragma unroll
  for (int k = 0; k < K; ++k) {
    if (l == k) {
      float* p = cf + (b * K + k) * 5;
      p[0] = cb0[k]; p[1] = cb1[k]; p[2] = cb2[k]; p[3] = ca1[k]; p[4] = ca2[k];
    }
  }

  // column l of one-sample homogeneous map A
  float col[NST];
  {
    float s1[K], s2[K];
#pragma unroll
    for (int k = 0; k < K; ++k) {
      s1[k] = (l == 2 * k) ? 1.0f : 0.0f;
      s2[k] = (l == 2 * k + 1) ? 1.0f : 0.0f;
    }
    float yv = 0.0f;
#pragma unroll
    for (int k = 0; k < K; ++k) {
      float yk = fmaf(cb0[k], yv, s1[k]);
      float t1 = fmaf(cb1[k], yv, s2[k]);
      float ns1 = fmaf(-ca1[k], yk, t1);
      float ns2 = fmaf(-ca2[k], yk, cb2[k] * yv);
      s1[k] = ns1; s2[k] = ns2; yv = yk;
    }
#pragma unroll
    for (int k = 0; k < K; ++k) { col[2 * k] = s1[k]; col[2 * k + 1] = s2[k]; }
  }

  auto square = [&]() {
    float nc[NST];
#pragma unroll
    for (int r = 0; r < NST; ++r) nc[r] = 0.0f;
#pragma unroll
    for (int m = 0; m < NST; ++m) {
      float wv = col[m];
#pragma unroll
      for (int r = 0; r < NST; ++r) nc[r] = fmaf(rl(col[r], m), wv, nc[r]);
    }
#pragma unroll
    for (int r = 0; r < NST; ++r) col[r] = nc[r];
  };
  auto dump = [&](float* G) {
    if (l < NST) {
#pragma unroll
      for (int r = 0; r < NST; ++r) G[(size_t)b * 144 + r * 12 + l] = col[r];
    }
  };

  for (int p = 0; p < SQ1; ++p) square();
  dump(ws + OFF_RL);
  for (int p = 0; p < SQ2; ++p) square();
  dump(ws + OFF_RW);
  for (int p = 0; p < SQ3; ++p) square();
  dump(ws + OFF_RC);
}

// Fused: phase1 zero-state finals -> block scan -> DECOUPLED publish of each
// block's own zero-state span -> consumer-side ordered fold of predecessors
// -> exact incoming per thread -> phase3 output from L3-warm re-read of x.
__global__ __launch_bounds__(256, 2) void eq_fused(const float* __restrict__ x,
                                                   float* __restrict__ ws,
                                                   float* __restrict__ y) {
  __shared__ float P1[NW][2][64][17];       // input staging
  __shared__ float U[NW * 2 * 64 * 17];     // scan structs / output staging
  __shared__ float BIN[16];                 // block incoming state

  const float* cf = ws + OFF_CF;
  float* states = ws + OFF_ST;
  unsigned* flags = (unsigned*)(ws + OFF_FL);

  int t = threadIdx.x, w = t >> 6, l = t & 63;
  int blk = blockIdx.x, row = blk / PB, p = blk % PB, b = row >> 1;
  bool act = (l < NST);

  // U overlays: phase2 = FB | SL | WF ; phase3 = sOut
  auto FBp = [&](int ww, int i, int r) -> float& { return U[(ww * 64 + i) * 13 + r]; };
  auto SLp = [&](int ww, int i, int r) -> float& { return U[3328 + (ww * 64 + i) * 13 + r]; };
  auto WFp = [&](int ww, int r) -> float& { return U[6656 + ww * 13 + r]; };
  auto SO = [&](int pb, int seg, int c) -> float& { return U[((w * 2 + pb) * 64 + seg) * 17 + c]; };

  const float4* xq = reinterpret_cast<const float4*>(
      x + (size_t)row * T + (size_t)p * CH + (size_t)w * (64 * SEGL));
  float4* yq = reinterpret_cast<float4*>(
      y + (size_t)row * T + (size_t)p * CH + (size_t)w * (64 * SEGL));

  int sj = l >> 2, qj = l & 3;

  // phase-1 prologue loads first (hide coeff/matrix loads under them)
  float4 ra[4], rb[4];
#pragma unroll
  for (int j = 0; j < 4; ++j) ra[j] = xq[(size_t)(j * 16 + sj) * Q4 + qj];
#pragma unroll
  for (int j = 0; j < 4; ++j) rb[j] = xq[(size_t)(j * 16 + sj) * Q4 + 4 + qj];

  float b0[K], b1c[K], b2c[K], a1c[K], a2c[K];
#pragma unroll
  for (int k = 0; k < K; ++k) {
    const float* cp = cf + (b * K + k) * 5;
    b0[k] = cp[0]; b1c[k] = cp[1]; b2c[k] = cp[2]; a1c[k] = cp[3]; a2c[k] = cp[4];
  }
  float rowL[NST], rowW[NST], rowC[NST];
#pragma unroll
  for (int m = 0; m < NST; ++m) {
    rowL[m] = act ? ws[OFF_RL + (size_t)b * 144 + l * 12 + m] : 0.0f;
    rowW[m] = act ? ws[OFF_RW + (size_t)b * 144 + l * 12 + m] : 0.0f;
    rowC[m] = act ? ws[OFF_RC + (size_t)b * 144 + l * 12 + m] : 0.0f;
  }

  float s1[K], s2[K];
#pragma unroll
  for (int k = 0; k < K; ++k) { s1[k] = 0.0f; s2[k] = 0.0f; }

  auto stage = [&](float4 (&r)[4], int pb) {
#pragma unroll
    for (int j = 0; j < 4; ++j) {
      int seg = j * 16 + sj;
      P1[w][pb][seg][qj * 4 + 0] = r[j].x;
      P1[w][pb][seg][qj * 4 + 1] = r[j].y;
      P1[w][pb][seg][qj * 4 + 2] = r[j].z;
      P1[w][pb][seg][qj * 4 + 3] = r[j].w;
    }
  };
  auto prefetch = [&](float4 (&r)[4], int tnext) {
    if (tnext < NT) {
#pragma unroll
      for (int j = 0; j < 4; ++j)
        r[j] = xq[(size_t)(j * 16 + sj) * Q4 + (size_t)tnext * 4 + qj];
    }
  };

  // ---- phase 1: zero-state pass, record per-thread finals
  for (int tt = 0; tt < NT; tt += 2) {
    stage(ra, 0);
    prefetch(ra, tt + 2);
#pragma unroll
    for (int i = 0; i < TS; ++i) {
      float yv = P1[w][0][l][i];
#pragma unroll
      for (int k = 0; k < K; ++k) {
        float yk = fmaf(b0[k], yv, s1[k]);
        float t1 = fmaf(b1c[k], yv, s2[k]);
        s1[k] = fmaf(-a1c[k], yk, t1);
        s2[k] = fmaf(-a2c[k], yk, b2c[k] * yv);
        yv = yk;
      }
    }
    stage(rb, 1);
    prefetch(rb, tt + 3);
#pragma unroll
    for (int i = 0; i < TS; ++i) {
      float yv = P1[w][1][l][i];
#pragma unroll
      for (int k = 0; k < K; ++k) {
        float yk = fmaf(b0[k], yv, s1[k]);
        float t1 = fmaf(b1c[k], yv, s2[k]);
        s1[k] = fmaf(-a1c[k], yk, t1);
        s2[k] = fmaf(-a2c[k], yk, b2c[k] * yv);
        yv = yk;
      }
    }
  }
#pragma unroll
  for (int k = 0; k < K; ++k) { FBp(w, l, 2 * k) = s1[k]; FBp(w, l, 2 * k + 1) = s2[k]; }
  __syncthreads();

  // ---- C1a: wave scan (zero incoming) -> wave final
  {
    float sv = 0.0f;
    for (int i = 0; i < 64; ++i) {
      float wv = act ? FBp(w, i, l) : 0.0f;
      sv = mv_step(rowL, sv) + wv;
    }
    if (act) WFp(w, l) = sv;
  }
  __syncthreads();

  // issue phase-3 prologue loads now (hide under publish/combine latency)
#pragma unroll
  for (int j = 0; j < 4; ++j) ra[j] = xq[(size_t)(j * 16 + sj) * Q4 + qj];
#pragma unroll
  for (int j = 0; j < 4; ++j) rb[j] = xq[(size_t)(j * 16 + sj) * Q4 + 4 + qj];

  // ---- decoupled lookback (wave 0):
  //  publish own zero-state span bz (no predecessor dependency), then fold
  //  all predecessors' bz in order: bin = sum_q Phi_c^(p-1-q) bz_q.
  if (w == 0) {
    float bz = 0.0f;
#pragma unroll
    for (int w2 = 0; w2 < NW; ++w2) {
      float wv = act ? WFp(w2, l) : 0.0f;
      bz = mv_step(rowW, bz) + wv;
    }
    if (p < PB - 1) {
      if (act)
        __hip_atomic_store((unsigned*)&states[(size_t)blk * NST + l],
                           __float_as_uint(bz), __ATOMIC_RELAXED,
                           __HIP_MEMORY_SCOPE_AGENT);
      if (l == 0)
        __hip_atomic_store(&flags[blk], 1u, __ATOMIC_RELEASE,
                           __HIP_MEMORY_SCOPE_AGENT);
    }
    float bin = 0.0f;
    for (int q = row * PB; q < blk; ++q) {
      if (act) {
        while (__hip_atomic_load(&flags[q], __ATOMIC_ACQUIRE,
                                 __HIP_MEMORY_SCOPE_AGENT) == 0u)
          __builtin_amdgcn_s_sleep(1);
        float bzq = __uint_as_float(__hip_atomic_load(
            (const unsigned*)&states[(size_t)q * NST + l], __ATOMIC_RELAXED,
            __HIP_MEMORY_SCOPE_AGENT));
        bin = mv_step(rowC, bin) + bzq;
      }
    }
    if (act) BIN[l] = bin;
  }
  __syncthreads();

  // ---- per-wave true incoming, then C1b stores per-segment incoming
  {
    float sv = act ? BIN[l] : 0.0f;
    for (int w2 = 0; w2 < w; ++w2) {
      float wv = act ? WFp(w2, l) : 0.0f;
      sv = mv_step(rowW, sv) + wv;
    }
    for (int i = 0; i < 64; ++i) {
      if (act) SLp(w, i, l) = sv;
      float wv = act ? FBp(w, i, l) : 0.0f;
      sv = mv_step(rowL, sv) + wv;
    }
  }
  // extract own incoming before U is reused as sOut
  float st[NST];
#pragma unroll
  for (int r = 0; r < NST; ++r) st[r] = SLp(w, l, r);
  __syncthreads();

  // ---- phase 3: exact pass, write output through full-line staging
#pragma unroll
  for (int k = 0; k < K; ++k) { s1[k] = st[2 * k]; s2[k] = st[2 * k + 1]; }

  auto flush = [&](int pb, int tt) {
#pragma unroll
    for (int j = 0; j < 4; ++j) {
      int seg = j * 16 + sj;
      float4 o;
      o.x = SO(pb, seg, qj * 4 + 0);
      o.y = SO(pb, seg, qj * 4 + 1);
      o.z = SO(pb, seg, qj * 4 + 2);
      o.w = SO(pb, seg, qj * 4 + 3);
      yq[(size_t)seg * Q4 + (size_t)tt * 4 + qj] = o;
    }
  };

  for (int tt = 0; tt < NT; tt += 2) {
    stage(ra, 0);
    prefetch(ra, tt + 2);
#pragma unroll
    for (int i = 0; i < TS; ++i) {
      float yv = P1[w][0][l][i];
#pragma unroll
      for (int k = 0; k < K; ++k) {
        float yk = fmaf(b0[k], yv, s1[k]);
        float t1 = fmaf(b1c[k], yv, s2[k]);
        s1[k] = fmaf(-a1c[k], yk, t1);
        s2[k] = fmaf(-a2c[k], yk, b2c[k] * yv);
        yv = yk;
      }
      SO(0, l, i) = yv;
    }
    flush(0, tt);
    stage(rb, 1);
    prefetch(rb, tt + 3);
#pragma unroll
    for (int i = 0; i < TS; ++i) {
      float yv = P1[w][1][l][i];
#pragma unroll
      for (int k = 0; k < K; ++k) {
        float yk = fmaf(b0[k], yv, s1[k]);
        float t1 = fmaf(b1c[k], yv, s2[k]);
        s1[k] = fmaf(-a1c[k], yk, t1);
        s2[k] = fmaf(-a2c[k], yk, b2c[k] * yv);
        yv = yk;
      }
      SO(1, l, i) = yv;
    }
    flush(1, tt + 1);
  }
}

extern "C" void kernel_launch(void* const* d_in, const int* in_sizes, int n_in,
                              void* d_out, int out_size, void* d_ws, size_t ws_size,
                              hipStream_t stream) {
  const float* audio = (const float*)d_in[0];
  const float* fr    = (const float*)d_in[1];
  const float* gn    = (const float*)d_in[2];
  const float* qf    = (const float*)d_in[3];
  float* out = (float*)d_out;
  float* ws = (float*)d_ws;

  // clear handshake flags (graph-capture-legal async memset)
  hipMemsetAsync((char*)d_ws + OFF_FL * sizeof(float), 0,
                 NBC * PB * sizeof(unsigned), stream);
  hipLaunchKernelGGL(eq_prep, dim3(B), dim3(64), 0, stream, fr, gn, qf, ws);
  hipLaunchKernelGGL(eq_fused, dim3(NBC * PB), dim3(256), 0, stream,
                     audio, ws, out);
}